// Round 7
// baseline (404.815 us; speedup 1.0000x reference)
//
#include <hip/hip_runtime.h>
#include <hip/hip_bf16.h>

// B=32, S=2048, H=512, fp32 in/out.
// scores = tanh(Y@W + b).w -> softmax(S) -> c_star = alpha@Y
// GEMM restructured: whole 128-col W-slice staged to LDS ONCE (128 KB),
// then a BARRIER-FREE main loop: A global->VGPR (coalesced 128B row lines),
// fp32->fp16 RNE cvt in registers, B from static LDS (chunk-XOR swizzle,
// conflict-free). No per-iter vmcnt(0) drains. 1 block/CU by design.

#define Bsz 32
#define Ssz 2048
#define Hsz 512
#define Msz (Bsz * Ssz)   // 65536

using half8   = __attribute__((ext_vector_type(8))) _Float16;
using floatx4 = __attribute__((ext_vector_type(4))) float;

__device__ __forceinline__ void llds16(void* l, const void* g) {
  __builtin_amdgcn_global_load_lds((const __attribute__((address_space(1))) void*)g,
                                   (__attribute__((address_space(3))) void*)l, 16, 0, 0);
}

__device__ __forceinline__ float fast_tanh(float x) {
  const float e = __expf(2.f * x);
  return 1.f - 2.f / (e + 1.f);
}

// ---- W[k][n] fp32 -> Wt[n][k] fp16 (transpose + RNE cast) ----
__global__ __launch_bounds__(256) void wsplit_k(const float* __restrict__ W,
                                                _Float16* __restrict__ Wt) {
  __shared__ float tile[32][33];
  const int bx = blockIdx.x & 15, by = blockIdx.x >> 4;
  const int tx = threadIdx.x & 31, ty = threadIdx.x >> 5;
#pragma unroll
  for (int i = 0; i < 4; ++i)
    tile[ty + 8 * i][tx] = W[(size_t)(by * 32 + ty + 8 * i) * Hsz + bx * 32 + tx];
  __syncthreads();
#pragma unroll
  for (int i = 0; i < 4; ++i) {
    const int n = bx * 32 + ty + 8 * i;
    const int k = by * 32 + tx;
    Wt[(size_t)n * Hsz + k] = (_Float16)tile[tx][ty + 8 * i];
  }
}

// ---- GEMM: block = 1024 rows x 128 cols; B static in LDS; no K-barriers ----
__global__ __launch_bounds__(256, 1) void gemm_score_k(const float* __restrict__ Y,
                                                       const _Float16* __restrict__ Wt,
                                                       const float* __restrict__ bvec,
                                                       const float* __restrict__ wvec,
                                                       float* __restrict__ scores4) {
  __shared__ __align__(16) _Float16 Bs[128 * 512];   // 128 KB, row = col of W
  const int tid = threadIdx.x;
  const int lane = tid & 63, wv = tid >> 6;
  const int lr = lane & 15, lq = lane >> 4;
  // nblk = g>>6: the 4 siblings sharing Y rows differ by 64 = 0 mod 8 -> same XCD.
  const int g = blockIdx.x;
  const int mblk = g & 63, nblk = g >> 6;

  // ---- stage B once: row r holds Wt[nblk*128+r][0..512) fp16 = 1KB.
  // LDS chunk slot s (16B) stores global chunk s ^ (r&7)  -> conflict-free reads.
  const _Float16* Wn = Wt + (size_t)(nblk * 128) * Hsz;
  for (int i = 0; i < 32; ++i) {
    const int r = i * 4 + wv;                     // wave-uniform row
    const int gc = lane ^ (r & 7);                // permuted 16B chunk in row
    llds16(&Bs[r * 512 + lane * 8], Wn + (size_t)r * Hsz + gc * 8);
  }
  float bb[8], ww[8];
#pragma unroll
  for (int cf = 0; cf < 8; ++cf) {
    const int col = nblk * 128 + cf * 16 + lr;
    bb[cf] = bvec[col];
    ww[cf] = wvec[col];
  }
  __syncthreads();   // the ONLY barrier

  // A base: lane's fragment rows/k (A-frag: m=lr, k=lq*8..+8)
  const float* aY = Y + ((size_t)(mblk * 1024 + wv * 32 + lr)) * Hsz + lq * 8;

#pragma unroll 1
  for (int mch = 0; mch < 8; ++mch) {
    const float* am = aY + (size_t)mch * 128 * Hsz;
    floatx4 acc[2][8];
#pragma unroll
    for (int rf = 0; rf < 2; ++rf)
#pragma unroll
      for (int cf = 0; cf < 8; ++cf)
        acc[rf][cf] = (floatx4){0.f, 0.f, 0.f, 0.f};

    float4 pa[2][2][2];   // [phase][rf][half16B]
#pragma unroll
    for (int rf = 0; rf < 2; ++rf) {
      const float4* p = (const float4*)(am + rf * 16 * Hsz);
      pa[0][rf][0] = p[0];
      pa[0][rf][1] = p[1];
    }

#pragma unroll
    for (int it = 0; it < 16; ++it) {
      const int cur = it & 1;
      if (it < 15) {
#pragma unroll
        for (int rf = 0; rf < 2; ++rf) {
          const float4* p = (const float4*)(am + rf * 16 * Hsz + (it + 1) * 32);
          pa[cur ^ 1][rf][0] = p[0];
          pa[cur ^ 1][rf][1] = p[1];
        }
      }
      half8 a[2];
#pragma unroll
      for (int rf = 0; rf < 2; ++rf) {
        const float4 f0 = pa[cur][rf][0], f1 = pa[cur][rf][1];
        half8 h;
        h[0] = (_Float16)f0.x; h[1] = (_Float16)f0.y;
        h[2] = (_Float16)f0.z; h[3] = (_Float16)f0.w;
        h[4] = (_Float16)f1.x; h[5] = (_Float16)f1.y;
        h[6] = (_Float16)f1.z; h[7] = (_Float16)f1.w;
        a[rf] = h;
      }
#pragma unroll
      for (int cf = 0; cf < 8; ++cf) {
        const int nr = cf * 16 + lr;
        const int slot = (it * 4 + lq) ^ (nr & 7);
        const half8 b = *(const half8*)&Bs[nr * 512 + slot * 8];
        acc[0][cf] = __builtin_amdgcn_mfma_f32_16x16x32_f16(a[0], b, acc[0][cf], 0, 0, 0);
        acc[1][cf] = __builtin_amdgcn_mfma_f32_16x16x32_f16(a[1], b, acc[1][cf], 0, 0, 0);
      }
    }

    // epilogue: score-partial for this m-chunk; wave-local (cols all in-wave).
#pragma unroll
    for (int rf = 0; rf < 2; ++rf) {
#pragma unroll
      for (int r = 0; r < 4; ++r) {
        float v = 0.f;
#pragma unroll
        for (int cf = 0; cf < 8; ++cf)
          v += fast_tanh(acc[rf][cf][r] + bb[cf]) * ww[cf];
        v += __shfl_xor(v, 1, 16);
        v += __shfl_xor(v, 2, 16);
        v += __shfl_xor(v, 4, 16);
        v += __shfl_xor(v, 8, 16);
        if (lr == 0)
          scores4[(size_t)nblk * Msz + mblk * 1024 + mch * 128 + wv * 32 +
                  rf * 16 + lq * 4 + r] = v;
      }
    }
  }
}

// ---- softmax over S, summing 4 nblk partials -> alpha ----
__global__ __launch_bounds__(256) void softmax_k(const float* __restrict__ scores4,
                                                 const float* __restrict__ mask,
                                                 float* __restrict__ alpha) {
  const int b = blockIdx.x, t = threadIdx.x;
  const int lane = t & 63, wv = t >> 6;
  float s[8];
  float mx = -3.4e38f;
#pragma unroll
  for (int i = 0; i < 8; ++i) {
    const int idx = b * Ssz + i * 256 + t;
    float v = scores4[idx] + scores4[Msz + idx] + scores4[2 * Msz + idx] + scores4[3 * Msz + idx];
    v -= 1000.f * (1.f - mask[idx]);
    s[i] = v;
    mx = fmaxf(mx, v);
  }
  for (int off = 32; off > 0; off >>= 1) mx = fmaxf(mx, __shfl_xor(mx, off, 64));
  __shared__ float rm[4], rs[4];
  if (lane == 0) rm[wv] = mx;
  __syncthreads();
  mx = fmaxf(fmaxf(rm[0], rm[1]), fmaxf(rm[2], rm[3]));
  float sum = 0.f;
#pragma unroll
  for (int i = 0; i < 8; ++i) {
    s[i] = __expf(s[i] - mx);
    sum += s[i];
  }
  for (int off = 32; off > 0; off >>= 1) sum += __shfl_xor(sum, off, 64);
  if (lane == 0) rs[wv] = sum;
  __syncthreads();
  sum = rs[0] + rs[1] + rs[2] + rs[3];
  const float inv = 1.f / sum;
#pragma unroll
  for (int i = 0; i < 8; ++i) alpha[b * Ssz + i * 256 + t] = s[i] * inv;
}

// ---- stage 1: partial sums of alpha*Y over 64-row slabs (contiguous 128KB) ----
__global__ __launch_bounds__(256) void wsum1_k(const float* __restrict__ alpha,
                                               const float* __restrict__ Y,
                                               float* __restrict__ partial) {
  const int b = blockIdx.x >> 5, sc = blockIdx.x & 31;
  const int t = threadIdx.x, lane = t & 63, wv = t >> 6;
  __shared__ float part[4 * 512];
  const int s0 = sc * 64 + wv * 16;
  const float* al = alpha + b * Ssz + s0;
  const float4* Yb = (const float4*)(Y + ((size_t)b * Ssz + s0) * Hsz);
  float a0 = 0.f, a1 = 0.f, a2 = 0.f, a3 = 0.f, a4 = 0.f, a5 = 0.f, a6 = 0.f, a7 = 0.f;
#pragma unroll 4
  for (int r = 0; r < 16; ++r) {
    const float a = al[r];
    const float4 y0 = Yb[r * 128 + lane * 2];
    const float4 y1 = Yb[r * 128 + lane * 2 + 1];
    a0 = fmaf(a, y0.x, a0); a1 = fmaf(a, y0.y, a1);
    a2 = fmaf(a, y0.z, a2); a3 = fmaf(a, y0.w, a3);
    a4 = fmaf(a, y1.x, a4); a5 = fmaf(a, y1.y, a5);
    a6 = fmaf(a, y1.z, a6); a7 = fmaf(a, y1.w, a7);
  }
  part[wv * 512 + 0 * 64 + lane] = a0;
  part[wv * 512 + 1 * 64 + lane] = a1;
  part[wv * 512 + 2 * 64 + lane] = a2;
  part[wv * 512 + 3 * 64 + lane] = a3;
  part[wv * 512 + 4 * 64 + lane] = a4;
  part[wv * 512 + 5 * 64 + lane] = a5;
  part[wv * 512 + 6 * 64 + lane] = a6;
  part[wv * 512 + 7 * 64 + lane] = a7;
  __syncthreads();
#pragma unroll
  for (int i = 0; i < 2; ++i) {
    const int h = i * 256 + t;
    const int idx = (h & 7) * 64 + (h >> 3);
    partial[((size_t)(b * 32 + sc)) * Hsz + h] =
        part[idx] + part[512 + idx] + part[1024 + idx] + part[1536 + idx];
  }
}

// ---- stage 2: out[b][h] = sum over 32 sc of partial ----
__global__ __launch_bounds__(256) void wsum2_k(const float* __restrict__ partial,
                                               float* __restrict__ out) {
  const int b = blockIdx.x >> 1;
  const int h = (blockIdx.x & 1) * 256 + threadIdx.x;
  float s = 0.f;
#pragma unroll 8
  for (int sc = 0; sc < 32; ++sc)
    s += partial[((size_t)(b * 32 + sc)) * Hsz + h];
  out[b * Hsz + h] = s;
}

extern "C" void kernel_launch(void* const* d_in, const int* in_sizes, int n_in,
                              void* d_out, int out_size, void* d_ws, size_t ws_size,
                              hipStream_t stream) {
  (void)in_sizes; (void)n_in; (void)out_size; (void)ws_size;
  const float* Y    = (const float*)d_in[0];
  const float* mask = (const float*)d_in[1];
  const float* W    = (const float*)d_in[2];
  const float* bvec = (const float*)d_in[3];
  const float* wvec = (const float*)d_in[4];
  float* out = (float*)d_out;

  char* ws = (char*)d_ws;
  _Float16* Wt   = (_Float16*)ws;                            // 512 KB
  float* scores4 = (float*)(ws + ((size_t)1 << 20));         // 1 MB (4 partials)
  float* alpha   = (float*)(ws + ((size_t)2 << 20));         // 256 KB
  float* partial = (float*)(ws + ((size_t)3 << 20));         // 2 MB

  wsplit_k<<<256, 256, 0, stream>>>(W, Wt);
  gemm_score_k<<<256, 256, 0, stream>>>(Y, Wt, bvec, wvec, scores4);
  softmax_k<<<Bsz, 256, 0, stream>>>(scores4, mask, alpha);
  wsum1_k<<<Bsz * 32, 256, 0, stream>>>(alpha, Y, partial);
  wsum2_k<<<Bsz * 2, 256, 0, stream>>>(partial, out);
}

// Round 8
// 275.338 us; speedup vs baseline: 1.4702x; 1.4702x over previous
//
#include <hip/hip_runtime.h>
#include <hip/hip_bf16.h>

// B=32, S=2048, H=512, fp32 in/out.
// scores = tanh(Y@W + b).w -> softmax(S) -> c_star = alpha@Y
// Model: gemm is bound by L3 delivery of Y (~5 TB/s). This round halves
// Y-derived traffic: N-split 2 (256 cols/block), tile M64 x N256 x BK32.
// A staged raw fp32 via llds (row-XOR swizzle), cvt fp32->fp16 after ds_read;
// B fp16 llds with proven 0-conflict swizzle. 2-barrier K-loop (R6 struct).

#define Bsz 32
#define Ssz 2048
#define Hsz 512
#define Msz (Bsz * Ssz)   // 65536

using half8   = __attribute__((ext_vector_type(8))) _Float16;
using floatx4 = __attribute__((ext_vector_type(4))) float;

__device__ __forceinline__ void llds16(void* l, const void* g) {
  __builtin_amdgcn_global_load_lds((const __attribute__((address_space(1))) void*)g,
                                   (__attribute__((address_space(3))) void*)l, 16, 0, 0);
}

__device__ __forceinline__ float fast_tanh(float x) {
  const float e = __expf(2.f * x);
  return 1.f - 2.f / (e + 1.f);
}

// ---- W[k][n] fp32 -> Wt[n][k] fp16 (transpose + RNE cast) ----
__global__ __launch_bounds__(256) void wsplit_k(const float* __restrict__ W,
                                                _Float16* __restrict__ Wt) {
  __shared__ float tile[32][33];
  const int bx = blockIdx.x & 15, by = blockIdx.x >> 4;
  const int tx = threadIdx.x & 31, ty = threadIdx.x >> 5;
#pragma unroll
  for (int i = 0; i < 4; ++i)
    tile[ty + 8 * i][tx] = W[(size_t)(by * 32 + ty + 8 * i) * Hsz + bx * 32 + tx];
  __syncthreads();
#pragma unroll
  for (int i = 0; i < 4; ++i) {
    const int n = bx * 32 + ty + 8 * i;
    const int k = by * 32 + tx;
    Wt[(size_t)n * Hsz + k] = (_Float16)tile[tx][ty + 8 * i];
  }
}

// ---- GEMM: M64 x N256 tile, 2 n-splits -> Y stream = 256MB (was 512) ----
__global__ __launch_bounds__(256) void gemm_score_k(const float* __restrict__ Y,
                                                    const _Float16* __restrict__ Wt,
                                                    const float* __restrict__ bvec,
                                                    const float* __restrict__ wvec,
                                                    float* __restrict__ scores2) {
  __shared__ __align__(16) float    As[64 * 32];    // 8 KB fp32, row-XOR swizzled
  __shared__ __align__(16) _Float16 Bs[256 * 32];   // 16 KB fp16, swizzled
  const int tid = threadIdx.x;
  const int lane = tid & 63, wv = tid >> 6;
  const int wr = wv >> 1, wc = wv & 1;
  const int lr = lane & 15, lq = lane >> 4;
  // siblings g=2m,2m+1 share the same 64-row Y slab -> concurrent L3 reuse
  const int g = blockIdx.x;
  const int mblk = g >> 1, nblk = g & 1;

  floatx4 acc[2][8];
#pragma unroll
  for (int rf = 0; rf < 2; ++rf)
#pragma unroll
    for (int cf = 0; cf < 8; ++cf)
      acc[rf][cf] = (floatx4){0.f, 0.f, 0.f, 0.f};

  const float* aY = Y + (size_t)mblk * 64 * Hsz;
  const _Float16* bW = Wt + (size_t)nblk * 256 * Hsz;

  for (int it = 0; it < 16; ++it) {
    const int k0 = it * 32;
    // A: 512 chunks of 16B (row = c>>3, 8 chunks per 128B row-slice).
    // LDS slot p stores global chunk (p&7)^(row&7) -> 2-way-max on read.
#pragma unroll
    for (int i = 0; i < 2; ++i) {
      const int cb = i * 256 + wv * 64;        // wave-uniform chunk base
      const int p = cb + lane;
      const int row = p >> 3;
      const int gc = (p & 7) ^ (row & 7);
      llds16(&As[cb * 4], aY + (size_t)row * Hsz + k0 + gc * 4);
    }
    // B: 1024 chunks (row = c>>2, 4 chunks per 64B row-slice), 0-conflict.
#pragma unroll
    for (int i = 0; i < 4; ++i) {
      const int cb = i * 256 + wv * 64;
      const int p = cb + lane;
      const int row = p >> 2;
      const int gc = (p & 3) ^ ((row >> 1) & 3);
      llds16(&Bs[cb * 8], bW + (size_t)row * Hsz + k0 + gc * 8);
    }
    __syncthreads();

    half8 a[2], bf[8];
#pragma unroll
    for (int rf = 0; rf < 2; ++rf) {
      const int ar = wr * 32 + rf * 16 + lr;
      const int s0 = (2 * lq) ^ (ar & 7);
      const float4 flo = *(const float4*)&As[ar * 32 + s0 * 4];
      const float4 fhi = *(const float4*)&As[ar * 32 + (s0 ^ 1) * 4];
      half8 h;
      h[0] = (_Float16)flo.x; h[1] = (_Float16)flo.y;
      h[2] = (_Float16)flo.z; h[3] = (_Float16)flo.w;
      h[4] = (_Float16)fhi.x; h[5] = (_Float16)fhi.y;
      h[6] = (_Float16)fhi.z; h[7] = (_Float16)fhi.w;
      a[rf] = h;
    }
#pragma unroll
    for (int cf = 0; cf < 8; ++cf) {
      const int nr = wc * 128 + cf * 16 + lr;
      bf[cf] = *(const half8*)&Bs[nr * 32 + (lq ^ ((nr >> 1) & 3)) * 8];
    }
#pragma unroll
    for (int cf = 0; cf < 8; ++cf) {
      acc[0][cf] = __builtin_amdgcn_mfma_f32_16x16x32_f16(a[0], bf[cf], acc[0][cf], 0, 0, 0);
      acc[1][cf] = __builtin_amdgcn_mfma_f32_16x16x32_f16(a[1], bf[cf], acc[1][cf], 0, 0, 0);
    }
    __syncthreads();
  }

  // Epilogue: v = sum over this block's 256 cols of tanh(pre+b)*w.
  // 16-lane shuffle reduce; combine the 2 col-waves via LDS; plain store.
  float bb[8], ww[8];
#pragma unroll
  for (int cf = 0; cf < 8; ++cf) {
    const int col = nblk * 256 + wc * 128 + cf * 16 + lr;
    bb[cf] = bvec[col];
    ww[cf] = wvec[col];
  }
  float* red = (float*)As;   // 128 floats
#pragma unroll
  for (int rf = 0; rf < 2; ++rf) {
#pragma unroll
    for (int r = 0; r < 4; ++r) {
      float v = 0.f;
#pragma unroll
      for (int cf = 0; cf < 8; ++cf)
        v += fast_tanh(acc[rf][cf][r] + bb[cf]) * ww[cf];
      v += __shfl_xor(v, 1, 16);
      v += __shfl_xor(v, 2, 16);
      v += __shfl_xor(v, 4, 16);
      v += __shfl_xor(v, 8, 16);
      if (lr == 0)
        red[(wr * 32 + rf * 16 + lq * 4 + r) * 2 + wc] = v;
    }
  }
  __syncthreads();
  if (tid < 64)
    scores2[(size_t)nblk * Msz + mblk * 64 + tid] = red[2 * tid] + red[2 * tid + 1];
}

// ---- softmax over S, summing 2 nblk partials -> alpha ----
__global__ __launch_bounds__(256) void softmax_k(const float* __restrict__ scores2,
                                                 const float* __restrict__ mask,
                                                 float* __restrict__ alpha) {
  const int b = blockIdx.x, t = threadIdx.x;
  const int lane = t & 63, wv = t >> 6;
  float s[8];
  float mx = -3.4e38f;
#pragma unroll
  for (int i = 0; i < 8; ++i) {
    const int idx = b * Ssz + i * 256 + t;
    float v = scores2[idx] + scores2[Msz + idx];
    v -= 1000.f * (1.f - mask[idx]);
    s[i] = v;
    mx = fmaxf(mx, v);
  }
  for (int off = 32; off > 0; off >>= 1) mx = fmaxf(mx, __shfl_xor(mx, off, 64));
  __shared__ float rm[4], rs[4];
  if (lane == 0) rm[wv] = mx;
  __syncthreads();
  mx = fmaxf(fmaxf(rm[0], rm[1]), fmaxf(rm[2], rm[3]));
  float sum = 0.f;
#pragma unroll
  for (int i = 0; i < 8; ++i) {
    s[i] = __expf(s[i] - mx);
    sum += s[i];
  }
  for (int off = 32; off > 0; off >>= 1) sum += __shfl_xor(sum, off, 64);
  if (lane == 0) rs[wv] = sum;
  __syncthreads();
  sum = rs[0] + rs[1] + rs[2] + rs[3];
  const float inv = 1.f / sum;
#pragma unroll
  for (int i = 0; i < 8; ++i) alpha[b * Ssz + i * 256 + t] = s[i] * inv;
}

// ---- stage 1: partial sums of alpha*Y over 64-row slabs (contiguous 128KB) ----
__global__ __launch_bounds__(256) void wsum1_k(const float* __restrict__ alpha,
                                               const float* __restrict__ Y,
                                               float* __restrict__ partial) {
  const int b = blockIdx.x >> 5, sc = blockIdx.x & 31;
  const int t = threadIdx.x, lane = t & 63, wv = t >> 6;
  __shared__ float part[4 * 512];
  const int s0 = sc * 64 + wv * 16;
  const float* al = alpha + b * Ssz + s0;
  const float4* Yb = (const float4*)(Y + ((size_t)b * Ssz + s0) * Hsz);
  float a0 = 0.f, a1 = 0.f, a2 = 0.f, a3 = 0.f, a4 = 0.f, a5 = 0.f, a6 = 0.f, a7 = 0.f;
#pragma unroll 4
  for (int r = 0; r < 16; ++r) {
    const float a = al[r];
    const float4 y0 = Yb[r * 128 + lane * 2];
    const float4 y1 = Yb[r * 128 + lane * 2 + 1];
    a0 = fmaf(a, y0.x, a0); a1 = fmaf(a, y0.y, a1);
    a2 = fmaf(a, y0.z, a2); a3 = fmaf(a, y0.w, a3);
    a4 = fmaf(a, y1.x, a4); a5 = fmaf(a, y1.y, a5);
    a6 = fmaf(a, y1.z, a6); a7 = fmaf(a, y1.w, a7);
  }
  part[wv * 512 + 0 * 64 + lane] = a0;
  part[wv * 512 + 1 * 64 + lane] = a1;
  part[wv * 512 + 2 * 64 + lane] = a2;
  part[wv * 512 + 3 * 64 + lane] = a3;
  part[wv * 512 + 4 * 64 + lane] = a4;
  part[wv * 512 + 5 * 64 + lane] = a5;
  part[wv * 512 + 6 * 64 + lane] = a6;
  part[wv * 512 + 7 * 64 + lane] = a7;
  __syncthreads();
#pragma unroll
  for (int i = 0; i < 2; ++i) {
    const int h = i * 256 + t;
    const int idx = (h & 7) * 64 + (h >> 3);
    partial[((size_t)(b * 32 + sc)) * Hsz + h] =
        part[idx] + part[512 + idx] + part[1024 + idx] + part[1536 + idx];
  }
}

// ---- stage 2: out[b][h] = sum over 32 sc of partial ----
__global__ __launch_bounds__(256) void wsum2_k(const float* __restrict__ partial,
                                               float* __restrict__ out) {
  const int b = blockIdx.x >> 1;
  const int h = (blockIdx.x & 1) * 256 + threadIdx.x;
  float s = 0.f;
#pragma unroll 8
  for (int sc = 0; sc < 32; ++sc)
    s += partial[((size_t)(b * 32 + sc)) * Hsz + h];
  out[b * Hsz + h] = s;
}

extern "C" void kernel_launch(void* const* d_in, const int* in_sizes, int n_in,
                              void* d_out, int out_size, void* d_ws, size_t ws_size,
                              hipStream_t stream) {
  (void)in_sizes; (void)n_in; (void)out_size; (void)ws_size;
  const float* Y    = (const float*)d_in[0];
  const float* mask = (const float*)d_in[1];
  const float* W    = (const float*)d_in[2];
  const float* bvec = (const float*)d_in[3];
  const float* wvec = (const float*)d_in[4];
  float* out = (float*)d_out;

  char* ws = (char*)d_ws;
  _Float16* Wt   = (_Float16*)ws;                            // 512 KB
  float* scores2 = (float*)(ws + ((size_t)1 << 20));         // 512 KB (2 partials)
  float* alpha   = (float*)(ws + ((size_t)2 << 20));         // 256 KB
  float* partial = (float*)(ws + ((size_t)3 << 20));         // 2 MB

  wsplit_k<<<256, 256, 0, stream>>>(W, Wt);
  gemm_score_k<<<(Msz / 64) * 2, 256, 0, stream>>>(Y, Wt, bvec, wvec, scores2);
  softmax_k<<<Bsz, 256, 0, stream>>>(scores2, mask, alpha);
  wsum1_k<<<Bsz * 32, 256, 0, stream>>>(alpha, Y, partial);
  wsum2_k<<<Bsz * 2, 256, 0, stream>>>(partial, out);
}

// Round 9
// 274.479 us; speedup vs baseline: 1.4749x; 1.0031x over previous
//
#include <hip/hip_runtime.h>
#include <hip/hip_bf16.h>

// B=32, S=2048, H=512, fp32 in/out.
// scores = tanh(Y@W + b).w -> softmax(S) -> c_star = alpha@Y
// Model test: gemm cost is per-barrier-iteration (~2000cyc), not per-byte.
// BK 32 -> 64: 8 K-iterations instead of 16, same M64xN256 tile, same
// swizzles (A raw fp32 llds row-XOR; B fp16 llds 0-conflict), 48 KB LDS.

#define Bsz 32
#define Ssz 2048
#define Hsz 512
#define Msz (Bsz * Ssz)   // 65536

using half8   = __attribute__((ext_vector_type(8))) _Float16;
using floatx4 = __attribute__((ext_vector_type(4))) float;

__device__ __forceinline__ void llds16(void* l, const void* g) {
  __builtin_amdgcn_global_load_lds((const __attribute__((address_space(1))) void*)g,
                                   (__attribute__((address_space(3))) void*)l, 16, 0, 0);
}

__device__ __forceinline__ float fast_tanh(float x) {
  const float e = __expf(2.f * x);
  return 1.f - 2.f / (e + 1.f);
}

// ---- W[k][n] fp32 -> Wt[n][k] fp16 (transpose + RNE cast) ----
__global__ __launch_bounds__(256) void wsplit_k(const float* __restrict__ W,
                                                _Float16* __restrict__ Wt) {
  __shared__ float tile[32][33];
  const int bx = blockIdx.x & 15, by = blockIdx.x >> 4;
  const int tx = threadIdx.x & 31, ty = threadIdx.x >> 5;
#pragma unroll
  for (int i = 0; i < 4; ++i)
    tile[ty + 8 * i][tx] = W[(size_t)(by * 32 + ty + 8 * i) * Hsz + bx * 32 + tx];
  __syncthreads();
#pragma unroll
  for (int i = 0; i < 4; ++i) {
    const int n = bx * 32 + ty + 8 * i;
    const int k = by * 32 + tx;
    Wt[(size_t)n * Hsz + k] = (_Float16)tile[tx][ty + 8 * i];
  }
}

// ---- GEMM: M64 x N256 x BK64; 8 two-barrier iterations ----
__global__ __launch_bounds__(256) void gemm_score_k(const float* __restrict__ Y,
                                                    const _Float16* __restrict__ Wt,
                                                    const float* __restrict__ bvec,
                                                    const float* __restrict__ wvec,
                                                    float* __restrict__ scores2) {
  // A: two 8KB k-sub-tiles [h][64 rows][8 chunks of 16B], row-XOR swizzled
  __shared__ __align__(16) float    As[1024 * 4];    // 16 KB
  // B: two 16KB k-sub-tiles [h][256 rows][4 chunks of 16B], swizzled
  __shared__ __align__(16) _Float16 Bs[2048 * 8];    // 32 KB
  const int tid = threadIdx.x;
  const int lane = tid & 63, wv = tid >> 6;
  const int wr = wv >> 1, wc = wv & 1;
  const int lr = lane & 15, lq = lane >> 4;
  const int g = blockIdx.x;
  const int mblk = g >> 1, nblk = g & 1;  // siblings share the Y slab

  floatx4 acc[2][8];
#pragma unroll
  for (int rf = 0; rf < 2; ++rf)
#pragma unroll
    for (int cf = 0; cf < 8; ++cf)
      acc[rf][cf] = (floatx4){0.f, 0.f, 0.f, 0.f};

  const float* aY = Y + (size_t)mblk * 64 * Hsz;
  const _Float16* bW = Wt + (size_t)nblk * 256 * Hsz;

  for (int it = 0; it < 8; ++it) {
    const int k0 = it * 64;
    // A: 1024 chunks. p -> h=p>>9, row=(p&511)>>3, slot c=p&7 stores gc=c^(row&7)
#pragma unroll
    for (int i = 0; i < 4; ++i) {
      const int cb = i * 256 + wv * 64;
      const int p = cb + lane;
      const int h = p >> 9, rem = p & 511;
      const int row = rem >> 3;
      const int gc = (rem & 7) ^ (row & 7);
      llds16(&As[cb * 4], aY + (size_t)row * Hsz + k0 + h * 32 + gc * 4);
    }
    // B: 2048 chunks. p -> h=p>>10, row=(p&1023)>>2, slot c=p&3 stores gc=c^((row>>1)&3)
#pragma unroll
    for (int i = 0; i < 8; ++i) {
      const int cb = i * 256 + wv * 64;
      const int p = cb + lane;
      const int h = p >> 10, rem = p & 1023;
      const int row = rem >> 2;
      const int gc = (rem & 3) ^ ((row >> 1) & 3);
      llds16(&Bs[cb * 8], bW + (size_t)row * Hsz + k0 + h * 32 + gc * 8);
    }
    __syncthreads();

#pragma unroll
    for (int h = 0; h < 2; ++h) {
      half8 a[2], bf[8];
#pragma unroll
      for (int rf = 0; rf < 2; ++rf) {
        const int ar = wr * 32 + rf * 16 + lr;
        const int s0 = (2 * lq) ^ (ar & 7);
        const float4 flo = *(const float4*)&As[(h * 512 + ar * 8 + s0) * 4];
        const float4 fhi = *(const float4*)&As[(h * 512 + ar * 8 + (s0 ^ 1)) * 4];
        half8 hh;
        hh[0] = (_Float16)flo.x; hh[1] = (_Float16)flo.y;
        hh[2] = (_Float16)flo.z; hh[3] = (_Float16)flo.w;
        hh[4] = (_Float16)fhi.x; hh[5] = (_Float16)fhi.y;
        hh[6] = (_Float16)fhi.z; hh[7] = (_Float16)fhi.w;
        a[rf] = hh;
      }
#pragma unroll
      for (int cf = 0; cf < 8; ++cf) {
        const int nr = wc * 128 + cf * 16 + lr;
        const int ck = h * 1024 + nr * 4 + (lq ^ ((nr >> 1) & 3));
        bf[cf] = *(const half8*)&Bs[ck * 8];
      }
#pragma unroll
      for (int cf = 0; cf < 8; ++cf) {
        acc[0][cf] = __builtin_amdgcn_mfma_f32_16x16x32_f16(a[0], bf[cf], acc[0][cf], 0, 0, 0);
        acc[1][cf] = __builtin_amdgcn_mfma_f32_16x16x32_f16(a[1], bf[cf], acc[1][cf], 0, 0, 0);
      }
    }
    __syncthreads();
  }

  // Epilogue: v = sum over this block's 256 cols of tanh(pre+b)*w.
  float bb[8], ww[8];
#pragma unroll
  for (int cf = 0; cf < 8; ++cf) {
    const int col = nblk * 256 + wc * 128 + cf * 16 + lr;
    bb[cf] = bvec[col];
    ww[cf] = wvec[col];
  }
  float* red = (float*)As;   // 128 floats
#pragma unroll
  for (int rf = 0; rf < 2; ++rf) {
#pragma unroll
    for (int r = 0; r < 4; ++r) {
      float v = 0.f;
#pragma unroll
      for (int cf = 0; cf < 8; ++cf)
        v += fast_tanh(acc[rf][cf][r] + bb[cf]) * ww[cf];
      v += __shfl_xor(v, 1, 16);
      v += __shfl_xor(v, 2, 16);
      v += __shfl_xor(v, 4, 16);
      v += __shfl_xor(v, 8, 16);
      if (lr == 0)
        red[(wr * 32 + rf * 16 + lq * 4 + r) * 2 + wc] = v;
    }
  }
  __syncthreads();
  if (tid < 64)
    scores2[(size_t)nblk * Msz + mblk * 64 + tid] = red[2 * tid] + red[2 * tid + 1];
}

// ---- softmax over S, summing 2 nblk partials -> alpha ----
__global__ __launch_bounds__(256) void softmax_k(const float* __restrict__ scores2,
                                                 const float* __restrict__ mask,
                                                 float* __restrict__ alpha) {
  const int b = blockIdx.x, t = threadIdx.x;
  const int lane = t & 63, wv = t >> 6;
  float s[8];
  float mx = -3.4e38f;
#pragma unroll
  for (int i = 0; i < 8; ++i) {
    const int idx = b * Ssz + i * 256 + t;
    float v = scores2[idx] + scores2[Msz + idx];
    v -= 1000.f * (1.f - mask[idx]);
    s[i] = v;
    mx = fmaxf(mx, v);
  }
  for (int off = 32; off > 0; off >>= 1) mx = fmaxf(mx, __shfl_xor(mx, off, 64));
  __shared__ float rm[4], rs[4];
  if (lane == 0) rm[wv] = mx;
  __syncthreads();
  mx = fmaxf(fmaxf(rm[0], rm[1]), fmaxf(rm[2], rm[3]));
  float sum = 0.f;
#pragma unroll
  for (int i = 0; i < 8; ++i) {
    s[i] = __expf(s[i] - mx);
    sum += s[i];
  }
  for (int off = 32; off > 0; off >>= 1) sum += __shfl_xor(sum, off, 64);
  if (lane == 0) rs[wv] = sum;
  __syncthreads();
  sum = rs[0] + rs[1] + rs[2] + rs[3];
  const float inv = 1.f / sum;
#pragma unroll
  for (int i = 0; i < 8; ++i) alpha[b * Ssz + i * 256 + t] = s[i] * inv;
}

// ---- stage 1: partial sums of alpha*Y over 64-row slabs (contiguous 128KB) ----
__global__ __launch_bounds__(256) void wsum1_k(const float* __restrict__ alpha,
                                               const float* __restrict__ Y,
                                               float* __restrict__ partial) {
  const int b = blockIdx.x >> 5, sc = blockIdx.x & 31;
  const int t = threadIdx.x, lane = t & 63, wv = t >> 6;
  __shared__ float part[4 * 512];
  const int s0 = sc * 64 + wv * 16;
  const float* al = alpha + b * Ssz + s0;
  const float4* Yb = (const float4*)(Y + ((size_t)b * Ssz + s0) * Hsz);
  float a0 = 0.f, a1 = 0.f, a2 = 0.f, a3 = 0.f, a4 = 0.f, a5 = 0.f, a6 = 0.f, a7 = 0.f;
#pragma unroll 4
  for (int r = 0; r < 16; ++r) {
    const float a = al[r];
    const float4 y0 = Yb[r * 128 + lane * 2];
    const float4 y1 = Yb[r * 128 + lane * 2 + 1];
    a0 = fmaf(a, y0.x, a0); a1 = fmaf(a, y0.y, a1);
    a2 = fmaf(a, y0.z, a2); a3 = fmaf(a, y0.w, a3);
    a4 = fmaf(a, y1.x, a4); a5 = fmaf(a, y1.y, a5);
    a6 = fmaf(a, y1.z, a6); a7 = fmaf(a, y1.w, a7);
  }
  part[wv * 512 + 0 * 64 + lane] = a0;
  part[wv * 512 + 1 * 64 + lane] = a1;
  part[wv * 512 + 2 * 64 + lane] = a2;
  part[wv * 512 + 3 * 64 + lane] = a3;
  part[wv * 512 + 4 * 64 + lane] = a4;
  part[wv * 512 + 5 * 64 + lane] = a5;
  part[wv * 512 + 6 * 64 + lane] = a6;
  part[wv * 512 + 7 * 64 + lane] = a7;
  __syncthreads();
#pragma unroll
  for (int i = 0; i < 2; ++i) {
    const int h = i * 256 + t;
    const int idx = (h & 7) * 64 + (h >> 3);
    partial[((size_t)(b * 32 + sc)) * Hsz + h] =
        part[idx] + part[512 + idx] + part[1024 + idx] + part[1536 + idx];
  }
}

// ---- stage 2: out[b][h] = sum over 32 sc of partial ----
__global__ __launch_bounds__(256) void wsum2_k(const float* __restrict__ partial,
                                               float* __restrict__ out) {
  const int b = blockIdx.x >> 1;
  const int h = (blockIdx.x & 1) * 256 + threadIdx.x;
  float s = 0.f;
#pragma unroll 8
  for (int sc = 0; sc < 32; ++sc)
    s += partial[((size_t)(b * 32 + sc)) * Hsz + h];
  out[b * Hsz + h] = s;
}

extern "C" void kernel_launch(void* const* d_in, const int* in_sizes, int n_in,
                              void* d_out, int out_size, void* d_ws, size_t ws_size,
                              hipStream_t stream) {
  (void)in_sizes; (void)n_in; (void)out_size; (void)ws_size;
  const float* Y    = (const float*)d_in[0];
  const float* mask = (const float*)d_in[1];
  const float* W    = (const float*)d_in[2];
  const float* bvec = (const float*)d_in[3];
  const float* wvec = (const float*)d_in[4];
  float* out = (float*)d_out;

  char* ws = (char*)d_ws;
  _Float16* Wt   = (_Float16*)ws;                            // 512 KB
  float* scores2 = (float*)(ws + ((size_t)1 << 20));         // 512 KB (2 partials)
  float* alpha   = (float*)(ws + ((size_t)2 << 20));         // 256 KB
  float* partial = (float*)(ws + ((size_t)3 << 20));         // 2 MB

  wsplit_k<<<256, 256, 0, stream>>>(W, Wt);
  gemm_score_k<<<(Msz / 64) * 2, 256, 0, stream>>>(Y, Wt, bvec, wvec, scores2);
  softmax_k<<<Bsz, 256, 0, stream>>>(scores2, mask, alpha);
  wsum1_k<<<Bsz * 32, 256, 0, stream>>>(alpha, Y, partial);
  wsum2_k<<<Bsz * 2, 256, 0, stream>>>(partial, out);
}